// Round 10
// baseline (390.526 us; speedup 1.0000x reference)
//
#include <hip/hip_runtime.h>
#include <stdint.h>

#define N_NODES  100000
#define N_EDGES  1600000
#define IN_FEATS 128
#define HID      32
#define N_REL    5
#define N_BASES  2
#define N_PAIRS  4096

#define NB        196        // buckets of 512 dst nodes
#define BS2       782        // bscatter blocks in fused kernel (2048 edges each)
#define T1BLKS    1250       // transform-L1 blocks in fused kernel (5 groups each)
#define NGROUPS   6250       // N_NODES/16

typedef __attribute__((ext_vector_type(8))) short short8;
typedef __attribute__((ext_vector_type(4))) float f32x4;

__device__ inline unsigned int pack_bf16(float a, float b) {
    unsigned int ua = __float_as_uint(a), ub = __float_as_uint(b);
    ua = (ua + 0x7fffu + ((ua >> 16) & 1u)) >> 16;
    ub = (ub + 0x7fffu + ((ub >> 16) & 1u)) >> 16;
    return ua | (ub << 16);
}

__device__ inline unsigned short bf16_1(float a) {
    unsigned int u = __float_as_uint(a);
    u = (u + 0x7fffu + ((u >> 16) & 1u)) >> 16;
    return (unsigned short)u;
}

// ---------------- fused weight-prep (blocks 0..143) + bucket count (144..534) ----------------

__global__ __launch_bounds__(256) void k_pre(
    const float* __restrict__ V1, const float* __restrict__ comp1, const float* __restrict__ loop1,
    const float* __restrict__ V2, const float* __restrict__ comp2, const float* __restrict__ loop2,
    const float* __restrict__ V3, const float* __restrict__ comp3, const float* __restrict__ loop3,
    unsigned short* __restrict__ Wbf1, unsigned short* __restrict__ Wbf2,
    unsigned short* __restrict__ Wbf3,
    const int* __restrict__ dst, int* __restrict__ ghist) {
    __shared__ int lh[NB];
    int b = blockIdx.x;
    int t = threadIdx.x;
    if (b < 144) {
        const float *V, *comp, *loopw;
        unsigned short* Wbf;
        int D, idx;
        if (b < 96)      { V = V1; comp = comp1; loopw = loop1; Wbf = Wbf1; D = IN_FEATS; idx = b * 256 + t; }
        else if (b < 120){ V = V2; comp = comp2; loopw = loop2; Wbf = Wbf2; D = HID;      idx = (b - 96) * 256 + t; }
        else             { V = V3; comp = comp3; loopw = loop3; Wbf = Wbf3; D = HID;      idx = (b - 120) * 256 + t; }
        if (idx >= 192 * D) return;
        int j = idx / D, k = idx % D;
        float v;
        if (j < 160) {
            int r = j >> 5, o = j & 31;
            v = comp[r * 2 + 0] * V[(size_t)(0 * D + k) * 32 + o]
              + comp[r * 2 + 1] * V[(size_t)(1 * D + k) * 32 + o];
        } else {
            v = loopw[k * 32 + (j - 160)];
        }
        Wbf[idx] = bf16_1(v);
    } else {
        int blk = b - 144;
        for (int i = t; i < NB; i += 256) lh[i] = 0;
        __syncthreads();
        int e0 = blk * 4096;
#pragma unroll
        for (int i = 0; i < 16; i++) {
            int e = e0 + t + i * 256;
            if (e < N_EDGES) atomicAdd(&lh[dst[e] >> 9], 1);
        }
        __syncthreads();
        for (int i = t; i < NB; i += 256) {
            int c = lh[i];
            if (c) atomicAdd(&ghist[i], c);
        }
    }
}

// ---------------- FUSED: bucket scatter (blocks 0..BS2-1) + transform L1 (rest) ----------------
// record: x = (dst&511)<<23 | (src*80 + etype*16), y = mask fp32

__global__ __launch_bounds__(256) void k_fuseB(
    const int* __restrict__ src, const int* __restrict__ dst,
    const int* __restrict__ etype, const float* __restrict__ mask,
    const int* __restrict__ ghist, int* __restrict__ gcur, int2* __restrict__ ebuf,
    const float* __restrict__ xin, const unsigned short* __restrict__ Wbf,
    const float* __restrict__ bias,
    unsigned short* __restrict__ xs16, float* __restrict__ aggout) {
    int t = threadIdx.x;
    if (blockIdx.x < BS2) {
        // ---------- bucket scatter: 2048 edges ----------
        __shared__ int lh[NB];
        __shared__ int lbase[NB];
        __shared__ int bs[NB];
        if (t < NB) lh[t] = 0;
        __syncthreads();
        int e0 = blockIdx.x * 2048;
#pragma unroll
        for (int i = 0; i < 8; i++) {
            int e = e0 + t + i * 256;
            if (e < N_EDGES) atomicAdd(&lh[dst[e] >> 9], 1);
        }
        __syncthreads();
        int gv = 0, c = 0;
        if (t < NB) { gv = ghist[t]; c = lh[t]; bs[t] = gv; }
        __syncthreads();
        for (int off = 1; off < 256; off <<= 1) {
            int v = 0;
            if (t < NB && t >= off) v = bs[t - off];
            __syncthreads();
            if (t < NB) bs[t] += v;
            __syncthreads();
        }
        if (t < NB) {
            int excl = bs[t] - gv;
            lbase[t] = excl + (c ? atomicAdd(&gcur[t], c) : 0);
            lh[t] = 0;
        }
        __syncthreads();
#pragma unroll
        for (int i = 0; i < 8; i++) {
            int e = e0 + t + i * 256;
            if (e < N_EDGES) {
                int d = dst[e];
                int b = d >> 9;
                int r = atomicAdd(&lh[b], 1);
                int2 pk;
                pk.x = ((d & 511) << 23) | (src[e] * 80 + etype[e] * 16);
                pk.y = __float_as_int(mask[e]);
                ebuf[lbase[b] + r] = pk;
            }
        }
    } else {
        // ---------- transform L1 (D=128), wave-specialized MFMA ----------
        __shared__ unsigned short As[16 * 136];
        int bi = blockIdx.x - BS2;
        int wv = t >> 6, lane = t & 63;
        int q = lane >> 4, n16 = lane & 15;
        short8 bfr[3][4];
#pragma unroll
        for (int i = 0; i < 3; i++) {
            int tt = wv * 3 + i;
#pragma unroll
            for (int ks = 0; ks < 4; ks++)
                bfr[i][ks] = *(const short8*)(Wbf + (tt * 16 + n16) * 128 + ks * 32 + q * 8);
        }
        float bv0 = bias[n16], bv1 = bias[16 + n16];
        int node_l = t >> 4;
        int seg    = t & 15;
        int g0 = bi * 5;
        float4 p0, p1;
        {
            const float* xr = xin + ((size_t)(g0 * 16 + node_l)) * 128 + seg * 8;
            p0 = *(const float4*)xr;
            p1 = *(const float4*)(xr + 4);
        }
        for (int gi = 0; gi < 5; gi++) {
            int g = g0 + gi;
            int n0 = g * 16;
            __syncthreads();
            {
                unsigned int u0 = pack_bf16(p0.x, p0.y);
                unsigned int u1 = pack_bf16(p0.z, p0.w);
                unsigned int u2 = pack_bf16(p1.x, p1.y);
                unsigned int u3 = pack_bf16(p1.z, p1.w);
                uint4 v; v.x = u0; v.y = u1; v.z = u2; v.w = u3;
                *(uint4*)(As + node_l * 136 + seg * 8) = v;
            }
            __syncthreads();
            if (gi + 1 < 5) {
                const float* xr = xin + ((size_t)((g + 1) * 16 + node_l)) * 128 + seg * 8;
                p0 = *(const float4*)xr;
                p1 = *(const float4*)(xr + 4);
            }
            short8 afr[4];
#pragma unroll
            for (int ks = 0; ks < 4; ks++)
                afr[ks] = *(const short8*)(As + n16 * 136 + ks * 32 + q * 8);
            f32x4 d[3];
            f32x4 z = {0.f, 0.f, 0.f, 0.f};
#pragma unroll
            for (int i = 0; i < 3; i++) d[i] = z;
#pragma unroll
            for (int i = 0; i < 3; i++)
#pragma unroll
                for (int ks = 0; ks < 4; ks++)
                    d[i] = __builtin_amdgcn_mfma_f32_16x16x32_bf16(afr[ks], bfr[i][ks], d[i], 0, 0, 0);
#pragma unroll
            for (int i = 0; i < 3; i++) {
                int tt = wv * 3 + i;
                if (tt < 10) {
#pragma unroll
                    for (int r = 0; r < 4; r++) {
                        int node = n0 + q * 4 + r;
                        xs16[(size_t)node * 160 + tt * 16 + n16] = bf16_1(d[i][r]);
                    }
                } else {
                    float bv = (tt == 10) ? bv0 : bv1;
                    int o = (tt - 10) * 16 + n16;
#pragma unroll
                    for (int r = 0; r < 4; r++) {
                        int node = n0 + q * 4 + r;
                        aggout[(size_t)node * 32 + o] = d[i][r] + bv;
                    }
                }
            }
        }
    }
}

// ---------------- per-half-bucket counting sort -> full CSR (esort + offsets) ----------------
// block = (bucket b, half h); full-bucket histogram+scan, write own half only.

__global__ __launch_bounds__(512) void k_bsort2(
    const int* __restrict__ ghist, const int2* __restrict__ ebuf,
    int2* __restrict__ esort, int* __restrict__ offsets) {
    __shared__ int hist[512];
    __shared__ int incl[512];
    __shared__ int cur[512];
    __shared__ int bs[256];
    __shared__ int sS0, sS1;
    int blk = blockIdx.x, b = blk >> 1, h = blk & 1, t = threadIdx.x;
    if (t < 256) bs[t] = (t < NB) ? ghist[t] : 0;
    __syncthreads();
    for (int off = 1; off < 256; off <<= 1) {
        int v = 0;
        if (t < 256 && t >= off) v = bs[t - off];
        __syncthreads();
        if (t < 256) bs[t] += v;
        __syncthreads();
    }
    if (t == 0) { sS1 = bs[b]; sS0 = bs[b] - ghist[b]; }
    hist[t] = 0;
    __syncthreads();
    int s0 = sS0, s1 = sS1;
    for (int e = s0 + t; e < s1; e += 512) {
        int dl = ((unsigned)ebuf[e].x) >> 23;
        atomicAdd(&hist[dl], 1);
    }
    __syncthreads();
    incl[t] = hist[t];
    __syncthreads();
    for (int off = 1; off < 512; off <<= 1) {
        int v = 0;
        if (t >= off) v = incl[t - off];
        __syncthreads();
        incl[t] += v;
        __syncthreads();
    }
    int ex = incl[t] - hist[t];
    cur[t] = ex;
    if ((t >> 8) == h) {
        int n = (b << 9) + t;
        if (n <= N_NODES) offsets[n] = s0 + ex;
    }
    if (b == NB - 1 && h == 1 && t == 0) offsets[N_NODES] = N_EDGES;
    __syncthreads();
    for (int e = s0 + t; e < s1; e += 512) {
        int2 pk = ebuf[e];
        int dl = ((unsigned)pk.x) >> 23;
        if ((dl >> 8) == h) {
            int pos = s0 + atomicAdd(&cur[dl], 1);
            int2 rec;
            rec.x = pk.x & 0x7fffff;
            rec.y = pk.y;
            esort[pos] = rec;
        }
    }
}

// ---------------- transform L2/L3 (D=32): B in registers, no LDS, no barrier ----------------

__global__ __launch_bounds__(256) void k_transform_reg32(
    const float* __restrict__ xin, int xstride,
    const unsigned short* __restrict__ Wbf, const float* __restrict__ bias,
    unsigned short* __restrict__ xs16, float* __restrict__ aggout) {
    int t = threadIdx.x;
    int wv = t >> 6, lane = t & 63;
    int q = lane >> 4, n16 = lane & 15;
    short8 bfr[12];
#pragma unroll
    for (int t12 = 0; t12 < 12; t12++)
        bfr[t12] = *(const short8*)(Wbf + (t12 * 16 + n16) * 32 + q * 8);
    float bv0 = bias[n16], bv1 = bias[16 + n16];
    int gstep = gridDim.x * 4;
    int g = blockIdx.x * 4 + wv;
    float4 x0, x1;
    if (g < NGROUPS) {
        const float* xr = xin + (size_t)(g * 16 + n16) * xstride + q * 8;
        x0 = *(const float4*)(xr);
        x1 = *(const float4*)(xr + 4);
    }
    while (g < NGROUPS) {
        int gn = g + gstep;
        union { unsigned int u[4]; short8 s; } cv;
        cv.u[0] = pack_bf16(x0.x, x0.y);
        cv.u[1] = pack_bf16(x0.z, x0.w);
        cv.u[2] = pack_bf16(x1.x, x1.y);
        cv.u[3] = pack_bf16(x1.z, x1.w);
        short8 afr = cv.s;
        float4 nx0, nx1;
        if (gn < NGROUPS) {
            const float* xr = xin + (size_t)(gn * 16 + n16) * xstride + q * 8;
            nx0 = *(const float4*)(xr);
            nx1 = *(const float4*)(xr + 4);
        }
        f32x4 d[12];
        f32x4 z = {0.f, 0.f, 0.f, 0.f};
#pragma unroll
        for (int i = 0; i < 12; i++) d[i] = z;
#pragma unroll
        for (int t12 = 0; t12 < 12; t12++)
            d[t12] = __builtin_amdgcn_mfma_f32_16x16x32_bf16(afr, bfr[t12], d[t12], 0, 0, 0);
        int n0 = g * 16;
#pragma unroll
        for (int t12 = 0; t12 < 10; t12++) {
#pragma unroll
            for (int r = 0; r < 4; r++) {
                int node = n0 + q * 4 + r;
                xs16[(size_t)node * 160 + t12 * 16 + n16] = bf16_1(d[t12][r]);
            }
        }
#pragma unroll
        for (int r = 0; r < 4; r++) {
            int node = n0 + q * 4 + r;
            aggout[(size_t)node * 32 + n16]      = d[10][r] + bv0;
            aggout[(size_t)node * 32 + 16 + n16] = d[11][r] + bv1;
        }
        x0 = nx0; x1 = nx1; g = gn;
    }
}

// ---------------- aggregation: 8 lanes/node, uint2 gathers, 16-deep, reg accumulate ----------------

__global__ __launch_bounds__(256) void k_agg(
    const int* __restrict__ offsets, const int2* __restrict__ esort,
    const unsigned int* __restrict__ xrel16, const float* __restrict__ agg,
    float* __restrict__ hout, int hoff) {
    int v = blockIdx.x * 32 + (threadIdx.x >> 3);
    int o = threadIdx.x & 7;
    if (v >= N_NODES) return;
    int s0 = offsets[v], s1 = offsets[v + 1];
    float4 a0 = *(const float4*)(agg + (size_t)v * 32 + o * 4);
    float acc0 = a0.x, acc1 = a0.y, acc2 = a0.z, acc3 = a0.w;
    int last = s1 - 1;
    for (int e = s0; e < s1; e += 16) {
        int addr[16];
        float m[16];
#pragma unroll
        for (int i = 0; i < 16; i++) {
            int ei = e + i;
            int ec = (ei <= last) ? ei : last;
            int2 pk = esort[ec];
            addr[i] = pk.x;
            m[i] = (ei <= last) ? __int_as_float(pk.y) : 0.f;
        }
        uint2 xw[16];
#pragma unroll
        for (int i = 0; i < 16; i++)
            xw[i] = *(const uint2*)(xrel16 + (unsigned)addr[i] + o * 2);
#pragma unroll
        for (int i = 0; i < 16; i++) {
            float f0 = __uint_as_float(xw[i].x << 16);
            float f1 = __uint_as_float(xw[i].x & 0xffff0000u);
            float f2 = __uint_as_float(xw[i].y << 16);
            float f3 = __uint_as_float(xw[i].y & 0xffff0000u);
            acc0 = fmaf(m[i], f0, acc0);
            acc1 = fmaf(m[i], f1, acc1);
            acc2 = fmaf(m[i], f2, acc2);
            acc3 = fmaf(m[i], f3, acc3);
        }
    }
    float4 r;
    r.x = tanhf(acc0); r.y = tanhf(acc1); r.z = tanhf(acc2); r.w = tanhf(acc3);
    *(float4*)(hout + (size_t)v * 96 + hoff + o * 4) = r;
}

// ---------------- MLP head ----------------

__global__ void k_mlp(const float* __restrict__ concat, const int* __restrict__ uidx,
                      const int* __restrict__ iidx,
                      const float* __restrict__ w1, const float* __restrict__ bw1,
                      const float* __restrict__ w2, const float* __restrict__ bw2,
                      float* __restrict__ out) {
    __shared__ float feats[192];
    __shared__ float red[2];
    int p = blockIdx.x;
    int t = threadIdx.x;   // 128 threads
    int u = uidx[p], it = iidx[p];
    for (int k = t; k < 192; k += 128)
        feats[k] = (k < 96) ? concat[(size_t)u * 96 + k] : concat[(size_t)it * 96 + (k - 96)];
    __syncthreads();
    float acc = bw1[t];
    for (int k = 0; k < 192; k++) acc += feats[k] * w1[k * 128 + t];
    float h = fmaxf(acc, 0.f);
    float part = h * w2[t];
    for (int off = 32; off > 0; off >>= 1) part += __shfl_down(part, off, 64);
    if ((t & 63) == 0) red[t >> 6] = part;
    __syncthreads();
    if (t == 0) out[p] = red[0] + red[1] + bw2[0];
}

// ---------------- launch ----------------

extern "C" void kernel_launch(void* const* d_in, const int* in_sizes, int n_in,
                              void* d_out, int out_size, void* d_ws, size_t ws_size,
                              hipStream_t stream) {
    const float* x         = (const float*)d_in[0];
    const float* edge_mask = (const float*)d_in[1];
    const int*   etype     = (const int*)d_in[2];
    const int*   src       = (const int*)d_in[3];
    const int*   dst       = (const int*)d_in[4];
    const int*   users_idx = (const int*)d_in[5];
    const int*   items_idx = (const int*)d_in[6];
    const float* V1        = (const float*)d_in[7];
    const float* comp1     = (const float*)d_in[8];
    const float* loop1     = (const float*)d_in[9];
    const float* b1        = (const float*)d_in[10];
    const float* V2        = (const float*)d_in[11];
    const float* comp2     = (const float*)d_in[12];
    const float* loop2     = (const float*)d_in[13];
    const float* b2        = (const float*)d_in[14];
    const float* V3        = (const float*)d_in[15];
    const float* comp3     = (const float*)d_in[16];
    const float* loop3     = (const float*)d_in[17];
    const float* b3        = (const float*)d_in[18];
    const float* w1        = (const float*)d_in[19];
    const float* bw1       = (const float*)d_in[20];
    const float* w2        = (const float*)d_in[21];
    const float* bw2       = (const float*)d_in[22];
    float* out = (float*)d_out;

    uintptr_t w = (uintptr_t)d_ws;
    auto al = [&](size_t bytes) { uintptr_t p = (w + 255) & ~(uintptr_t)255; w = p + bytes; return p; };
    int*   ghist   = (int*)al(sizeof(int) * 2 * NB);   // ghist[NB] then gcur[NB]
    int*   gcur    = ghist + NB;
    int*   offsets = (int*)al(sizeof(int) * (N_NODES + 1));
    int2*  ebuf    = (int2*)al(sizeof(int2) * N_EDGES);          // un-aliased: fused kernel
    unsigned int* xrel16 = (unsigned int*)al(sizeof(unsigned int) * (size_t)N_NODES * 80);
    int2*  esort   = (int2*)al(sizeof(int2) * N_EDGES);
    unsigned short* Wbf1 = (unsigned short*)al(sizeof(unsigned short) * 192 * IN_FEATS);
    unsigned short* Wbf2 = (unsigned short*)al(sizeof(unsigned short) * 192 * HID);
    unsigned short* Wbf3 = (unsigned short*)al(sizeof(unsigned short) * 192 * HID);
    float* agg     = (float*)al(sizeof(float) * (size_t)N_NODES * 32);
    float* concat  = (float*)al(sizeof(float) * (size_t)N_NODES * 96);

    hipMemsetAsync(ghist, 0, sizeof(int) * 2 * NB, stream);

    k_pre<<<144 + 391, 256, 0, stream>>>(V1, comp1, loop1, V2, comp2, loop2,
                                         V3, comp3, loop3, Wbf1, Wbf2, Wbf3,
                                         dst, ghist);
    // fused: bucket scatter + layer-1 transform (independent, both need only k_pre)
    k_fuseB<<<BS2 + T1BLKS, 256, 0, stream>>>(src, dst, etype, edge_mask, ghist, gcur, ebuf,
                                              x, Wbf1, b1, (unsigned short*)xrel16, agg);
    k_bsort2<<<2 * NB, 512, 0, stream>>>(ghist, ebuf, esort, offsets);

    const int agrid = (N_NODES + 31) / 32;

    k_agg<<<agrid, 256, 0, stream>>>(offsets, esort, xrel16, agg, concat, 0);

    k_transform_reg32<<<784, 256, 0, stream>>>(concat + 0, 96, Wbf2, b2, (unsigned short*)xrel16, agg);
    k_agg<<<agrid, 256, 0, stream>>>(offsets, esort, xrel16, agg, concat, 32);

    k_transform_reg32<<<784, 256, 0, stream>>>(concat + 32, 96, Wbf3, b3, (unsigned short*)xrel16, agg);
    k_agg<<<agrid, 256, 0, stream>>>(offsets, esort, xrel16, agg, concat, 64);

    k_mlp<<<N_PAIRS, 128, 0, stream>>>(concat, users_idx, items_idx, w1, bw1, w2, bw2, out);
}

// Round 11
// 378.638 us; speedup vs baseline: 1.0314x; 1.0314x over previous
//
#include <hip/hip_runtime.h>
#include <stdint.h>

#define N_NODES  100000
#define N_EDGES  1600000
#define IN_FEATS 128
#define HID      32
#define N_REL    5
#define N_BASES  2
#define N_PAIRS  4096

#define NB        196        // buckets of 512 dst nodes
#define BCAP      16384      // fixed slab per bucket in ebuf (mean 8192, sigma ~90)
#define BS_BLOCKS 782        // bscatter blocks (2048 edges each)
#define NGROUPS   6250       // N_NODES/16

typedef __attribute__((ext_vector_type(8))) short short8;
typedef __attribute__((ext_vector_type(4))) float f32x4;

__device__ inline unsigned int pack_bf16(float a, float b) {
    unsigned int ua = __float_as_uint(a), ub = __float_as_uint(b);
    ua = (ua + 0x7fffu + ((ua >> 16) & 1u)) >> 16;
    ub = (ub + 0x7fffu + ((ub >> 16) & 1u)) >> 16;
    return ua | (ub << 16);
}

__device__ inline unsigned short bf16_1(float a) {
    unsigned int u = __float_as_uint(a);
    u = (u + 0x7fffu + ((u >> 16) & 1u)) >> 16;
    return (unsigned short)u;
}

// ---------------- weight prep only: Wbf[j][k] bf16 for all three layers ----------------

__global__ __launch_bounds__(256) void k_prew(
    const float* __restrict__ V1, const float* __restrict__ comp1, const float* __restrict__ loop1,
    const float* __restrict__ V2, const float* __restrict__ comp2, const float* __restrict__ loop2,
    const float* __restrict__ V3, const float* __restrict__ comp3, const float* __restrict__ loop3,
    unsigned short* __restrict__ Wbf1, unsigned short* __restrict__ Wbf2,
    unsigned short* __restrict__ Wbf3) {
    int b = blockIdx.x;
    int t = threadIdx.x;
    const float *V, *comp, *loopw;
    unsigned short* Wbf;
    int D, idx;
    if (b < 96)      { V = V1; comp = comp1; loopw = loop1; Wbf = Wbf1; D = IN_FEATS; idx = b * 256 + t; }
    else if (b < 120){ V = V2; comp = comp2; loopw = loop2; Wbf = Wbf2; D = HID;      idx = (b - 96) * 256 + t; }
    else             { V = V3; comp = comp3; loopw = loop3; Wbf = Wbf3; D = HID;      idx = (b - 120) * 256 + t; }
    if (idx >= 192 * D) return;
    int j = idx / D, k = idx % D;
    float v;
    if (j < 160) {
        int r = j >> 5, o = j & 31;
        v = comp[r * 2 + 0] * V[(size_t)(0 * D + k) * 32 + o]
          + comp[r * 2 + 1] * V[(size_t)(1 * D + k) * 32 + o];
    } else {
        v = loopw[k * 32 + (j - 160)];
    }
    Wbf[idx] = bf16_1(v);
}

// ---------------- bucket scatter into fixed slabs (no count pass needed) ----------------
// record: x = (dst&511)<<23 | (src*80 + etype*16), y = mask fp32
// bucket b's records live at ebuf[b*BCAP .. b*BCAP+gcur[b])

__global__ __launch_bounds__(256) void k_bscatter(
    const int* __restrict__ src, const int* __restrict__ dst,
    const int* __restrict__ etype, const float* __restrict__ mask,
    int* __restrict__ gcur, int2* __restrict__ ebuf) {
    __shared__ int lh[NB];
    __shared__ int lbase[NB];
    int t = threadIdx.x;
    if (t < NB) lh[t] = 0;
    __syncthreads();
    int e0 = blockIdx.x * 2048;
#pragma unroll
    for (int i = 0; i < 8; i++) {
        int e = e0 + t + i * 256;
        if (e < N_EDGES) atomicAdd(&lh[dst[e] >> 9], 1);
    }
    __syncthreads();
    if (t < NB) {
        int c = lh[t];
        lbase[t] = t * BCAP + (c ? atomicAdd(&gcur[t], c) : 0);
        lh[t] = 0;
    }
    __syncthreads();
#pragma unroll
    for (int i = 0; i < 8; i++) {
        int e = e0 + t + i * 256;
        if (e < N_EDGES) {
            int d = dst[e];
            int b = d >> 9;
            int r = atomicAdd(&lh[b], 1);
            int2 pk;
            pk.x = ((d & 511) << 23) | (src[e] * 80 + etype[e] * 16);
            pk.y = __float_as_int(mask[e]);
            ebuf[lbase[b] + r] = pk;
        }
    }
}

// ---------------- per-half-bucket counting sort -> contiguous CSR (esort + offsets) ----------------
// block = (bucket b, half h); global bases from in-block scan of gcur counts.

__global__ __launch_bounds__(512) void k_bsort2(
    const int* __restrict__ gcur, const int2* __restrict__ ebuf,
    int2* __restrict__ esort, int* __restrict__ offsets) {
    __shared__ int hist[512];
    __shared__ int incl[512];
    __shared__ int cur[512];
    __shared__ int bs[256];
    __shared__ int sBase, sCnt;
    int blk = blockIdx.x, b = blk >> 1, h = blk & 1, t = threadIdx.x;
    if (t < 256) bs[t] = (t < NB) ? gcur[t] : 0;
    __syncthreads();
    for (int off = 1; off < 256; off <<= 1) {
        int v = 0;
        if (t < 256 && t >= off) v = bs[t - off];
        __syncthreads();
        if (t < 256) bs[t] += v;
        __syncthreads();
    }
    if (t == 0) { sCnt = gcur[b]; sBase = bs[b] - gcur[b]; }
    hist[t] = 0;
    __syncthreads();
    int cnt = sCnt, gbase = sBase;
    const int2* slab = ebuf + (size_t)b * BCAP;
    for (int e = t; e < cnt; e += 512) {
        int dl = ((unsigned)slab[e].x) >> 23;
        atomicAdd(&hist[dl], 1);
    }
    __syncthreads();
    incl[t] = hist[t];
    __syncthreads();
    for (int off = 1; off < 512; off <<= 1) {
        int v = 0;
        if (t >= off) v = incl[t - off];
        __syncthreads();
        incl[t] += v;
        __syncthreads();
    }
    int ex = incl[t] - hist[t];
    cur[t] = ex;
    if ((t >> 8) == h) {
        int n = (b << 9) + t;
        if (n <= N_NODES) offsets[n] = gbase + ex;
    }
    if (b == NB - 1 && h == 1 && t == 0) offsets[N_NODES] = N_EDGES;
    __syncthreads();
    for (int e = t; e < cnt; e += 512) {
        int2 pk = slab[e];
        int dl = ((unsigned)pk.x) >> 23;
        if ((dl >> 8) == h) {
            int pos = gbase + atomicAdd(&cur[dl], 1);
            int2 rec;
            rec.x = pk.x & 0x7fffff;
            rec.y = pk.y;
            esort[pos] = rec;
        }
    }
}

// ---------------- transform L1 (D=128): wave-specialized MFMA ----------------

__global__ __launch_bounds__(256) void k_transform_l1(
    const float* __restrict__ xin,
    const unsigned short* __restrict__ Wbf, const float* __restrict__ bias,
    unsigned short* __restrict__ xs16, float* __restrict__ aggout) {
    __shared__ unsigned short As[16 * 136];
    int t = threadIdx.x;
    int wv = t >> 6, lane = t & 63;
    int q = lane >> 4, n16 = lane & 15;
    short8 bfr[3][4];
#pragma unroll
    for (int i = 0; i < 3; i++) {
        int tt = wv * 3 + i;
#pragma unroll
        for (int ks = 0; ks < 4; ks++)
            bfr[i][ks] = *(const short8*)(Wbf + (tt * 16 + n16) * 128 + ks * 32 + q * 8);
    }
    float bv0 = bias[n16], bv1 = bias[16 + n16];
    int node_l = t >> 4;
    int seg    = t & 15;
    int g0 = blockIdx.x * 5;
    float4 p0, p1;
    {
        const float* xr = xin + ((size_t)(g0 * 16 + node_l)) * 128 + seg * 8;
        p0 = *(const float4*)xr;
        p1 = *(const float4*)(xr + 4);
    }
    for (int gi = 0; gi < 5; gi++) {
        int g = g0 + gi;
        int n0 = g * 16;
        __syncthreads();
        {
            unsigned int u0 = pack_bf16(p0.x, p0.y);
            unsigned int u1 = pack_bf16(p0.z, p0.w);
            unsigned int u2 = pack_bf16(p1.x, p1.y);
            unsigned int u3 = pack_bf16(p1.z, p1.w);
            uint4 v; v.x = u0; v.y = u1; v.z = u2; v.w = u3;
            *(uint4*)(As + node_l * 136 + seg * 8) = v;
        }
        __syncthreads();
        if (gi + 1 < 5) {
            const float* xr = xin + ((size_t)((g + 1) * 16 + node_l)) * 128 + seg * 8;
            p0 = *(const float4*)xr;
            p1 = *(const float4*)(xr + 4);
        }
        short8 afr[4];
#pragma unroll
        for (int ks = 0; ks < 4; ks++)
            afr[ks] = *(const short8*)(As + n16 * 136 + ks * 32 + q * 8);
        f32x4 d[3];
        f32x4 z = {0.f, 0.f, 0.f, 0.f};
#pragma unroll
        for (int i = 0; i < 3; i++) d[i] = z;
#pragma unroll
        for (int i = 0; i < 3; i++)
#pragma unroll
            for (int ks = 0; ks < 4; ks++)
                d[i] = __builtin_amdgcn_mfma_f32_16x16x32_bf16(afr[ks], bfr[i][ks], d[i], 0, 0, 0);
#pragma unroll
        for (int i = 0; i < 3; i++) {
            int tt = wv * 3 + i;
            if (tt < 10) {
#pragma unroll
                for (int r = 0; r < 4; r++) {
                    int node = n0 + q * 4 + r;
                    xs16[(size_t)node * 160 + tt * 16 + n16] = bf16_1(d[i][r]);
                }
            } else {
                float bv = (tt == 10) ? bv0 : bv1;
                int o = (tt - 10) * 16 + n16;
#pragma unroll
                for (int r = 0; r < 4; r++) {
                    int node = n0 + q * 4 + r;
                    aggout[(size_t)node * 32 + o] = d[i][r] + bv;
                }
            }
        }
    }
}

// ---------------- transform L2/L3 (D=32): B in registers, no LDS, no barrier ----------------

__global__ __launch_bounds__(256) void k_transform_reg32(
    const float* __restrict__ xin, int xstride,
    const unsigned short* __restrict__ Wbf, const float* __restrict__ bias,
    unsigned short* __restrict__ xs16, float* __restrict__ aggout) {
    int t = threadIdx.x;
    int wv = t >> 6, lane = t & 63;
    int q = lane >> 4, n16 = lane & 15;
    short8 bfr[12];
#pragma unroll
    for (int t12 = 0; t12 < 12; t12++)
        bfr[t12] = *(const short8*)(Wbf + (t12 * 16 + n16) * 32 + q * 8);
    float bv0 = bias[n16], bv1 = bias[16 + n16];
    int gstep = gridDim.x * 4;
    int g = blockIdx.x * 4 + wv;
    float4 x0, x1;
    if (g < NGROUPS) {
        const float* xr = xin + (size_t)(g * 16 + n16) * xstride + q * 8;
        x0 = *(const float4*)(xr);
        x1 = *(const float4*)(xr + 4);
    }
    while (g < NGROUPS) {
        int gn = g + gstep;
        union { unsigned int u[4]; short8 s; } cv;
        cv.u[0] = pack_bf16(x0.x, x0.y);
        cv.u[1] = pack_bf16(x0.z, x0.w);
        cv.u[2] = pack_bf16(x1.x, x1.y);
        cv.u[3] = pack_bf16(x1.z, x1.w);
        short8 afr = cv.s;
        float4 nx0, nx1;
        if (gn < NGROUPS) {
            const float* xr = xin + (size_t)(gn * 16 + n16) * xstride + q * 8;
            nx0 = *(const float4*)(xr);
            nx1 = *(const float4*)(xr + 4);
        }
        f32x4 d[12];
        f32x4 z = {0.f, 0.f, 0.f, 0.f};
#pragma unroll
        for (int i = 0; i < 12; i++) d[i] = z;
#pragma unroll
        for (int t12 = 0; t12 < 12; t12++)
            d[t12] = __builtin_amdgcn_mfma_f32_16x16x32_bf16(afr, bfr[t12], d[t12], 0, 0, 0);
        int n0 = g * 16;
#pragma unroll
        for (int t12 = 0; t12 < 10; t12++) {
#pragma unroll
            for (int r = 0; r < 4; r++) {
                int node = n0 + q * 4 + r;
                xs16[(size_t)node * 160 + t12 * 16 + n16] = bf16_1(d[t12][r]);
            }
        }
#pragma unroll
        for (int r = 0; r < 4; r++) {
            int node = n0 + q * 4 + r;
            aggout[(size_t)node * 32 + n16]      = d[10][r] + bv0;
            aggout[(size_t)node * 32 + 16 + n16] = d[11][r] + bv1;
        }
        x0 = nx0; x1 = nx1; g = gn;
    }
}

// ---------------- aggregation: 8 lanes/node, uint2 gathers, 16-deep, reg accumulate ----------------

__global__ __launch_bounds__(256) void k_agg(
    const int* __restrict__ offsets, const int2* __restrict__ esort,
    const unsigned int* __restrict__ xrel16, const float* __restrict__ agg,
    float* __restrict__ hout, int hoff) {
    int v = blockIdx.x * 32 + (threadIdx.x >> 3);
    int o = threadIdx.x & 7;
    if (v >= N_NODES) return;
    int s0 = offsets[v], s1 = offsets[v + 1];
    float4 a0 = *(const float4*)(agg + (size_t)v * 32 + o * 4);
    float acc0 = a0.x, acc1 = a0.y, acc2 = a0.z, acc3 = a0.w;
    int last = s1 - 1;
    for (int e = s0; e < s1; e += 16) {
        int addr[16];
        float m[16];
#pragma unroll
        for (int i = 0; i < 16; i++) {
            int ei = e + i;
            int ec = (ei <= last) ? ei : last;
            int2 pk = esort[ec];
            addr[i] = pk.x;
            m[i] = (ei <= last) ? __int_as_float(pk.y) : 0.f;
        }
        uint2 xw[16];
#pragma unroll
        for (int i = 0; i < 16; i++)
            xw[i] = *(const uint2*)(xrel16 + (unsigned)addr[i] + o * 2);
#pragma unroll
        for (int i = 0; i < 16; i++) {
            float f0 = __uint_as_float(xw[i].x << 16);
            float f1 = __uint_as_float(xw[i].x & 0xffff0000u);
            float f2 = __uint_as_float(xw[i].y << 16);
            float f3 = __uint_as_float(xw[i].y & 0xffff0000u);
            acc0 = fmaf(m[i], f0, acc0);
            acc1 = fmaf(m[i], f1, acc1);
            acc2 = fmaf(m[i], f2, acc2);
            acc3 = fmaf(m[i], f3, acc3);
        }
    }
    float4 r;
    r.x = tanhf(acc0); r.y = tanhf(acc1); r.z = tanhf(acc2); r.w = tanhf(acc3);
    *(float4*)(hout + (size_t)v * 96 + hoff + o * 4) = r;
}

// ---------------- MLP head ----------------

__global__ void k_mlp(const float* __restrict__ concat, const int* __restrict__ uidx,
                      const int* __restrict__ iidx,
                      const float* __restrict__ w1, const float* __restrict__ bw1,
                      const float* __restrict__ w2, const float* __restrict__ bw2,
                      float* __restrict__ out) {
    __shared__ float feats[192];
    __shared__ float red[2];
    int p = blockIdx.x;
    int t = threadIdx.x;   // 128 threads
    int u = uidx[p], it = iidx[p];
    for (int k = t; k < 192; k += 128)
        feats[k] = (k < 96) ? concat[(size_t)u * 96 + k] : concat[(size_t)it * 96 + (k - 96)];
    __syncthreads();
    float acc = bw1[t];
    for (int k = 0; k < 192; k++) acc += feats[k] * w1[k * 128 + t];
    float h = fmaxf(acc, 0.f);
    float part = h * w2[t];
    for (int off = 32; off > 0; off >>= 1) part += __shfl_down(part, off, 64);
    if ((t & 63) == 0) red[t >> 6] = part;
    __syncthreads();
    if (t == 0) out[p] = red[0] + red[1] + bw2[0];
}

// ---------------- launch ----------------

extern "C" void kernel_launch(void* const* d_in, const int* in_sizes, int n_in,
                              void* d_out, int out_size, void* d_ws, size_t ws_size,
                              hipStream_t stream) {
    const float* x         = (const float*)d_in[0];
    const float* edge_mask = (const float*)d_in[1];
    const int*   etype     = (const int*)d_in[2];
    const int*   src       = (const int*)d_in[3];
    const int*   dst       = (const int*)d_in[4];
    const int*   users_idx = (const int*)d_in[5];
    const int*   items_idx = (const int*)d_in[6];
    const float* V1        = (const float*)d_in[7];
    const float* comp1     = (const float*)d_in[8];
    const float* loop1     = (const float*)d_in[9];
    const float* b1        = (const float*)d_in[10];
    const float* V2        = (const float*)d_in[11];
    const float* comp2     = (const float*)d_in[12];
    const float* loop2     = (const float*)d_in[13];
    const float* b2        = (const float*)d_in[14];
    const float* V3        = (const float*)d_in[15];
    const float* comp3     = (const float*)d_in[16];
    const float* loop3     = (const float*)d_in[17];
    const float* b3        = (const float*)d_in[18];
    const float* w1        = (const float*)d_in[19];
    const float* bw1       = (const float*)d_in[20];
    const float* w2        = (const float*)d_in[21];
    const float* bw2       = (const float*)d_in[22];
    float* out = (float*)d_out;

    uintptr_t w = (uintptr_t)d_ws;
    auto al = [&](size_t bytes) { uintptr_t p = (w + 255) & ~(uintptr_t)255; w = p + bytes; return p; };
    int*   gcur    = (int*)al(sizeof(int) * NB);
    int*   offsets = (int*)al(sizeof(int) * (N_NODES + 1));
    int2*  ebuf    = (int2*)al(sizeof(int2) * (size_t)NB * BCAP);   // fixed slabs
    unsigned int* xrel16 = (unsigned int*)al(sizeof(unsigned int) * (size_t)N_NODES * 80);
    int2*  esort   = (int2*)al(sizeof(int2) * N_EDGES);
    unsigned short* Wbf1 = (unsigned short*)al(sizeof(unsigned short) * 192 * IN_FEATS);
    unsigned short* Wbf2 = (unsigned short*)al(sizeof(unsigned short) * 192 * HID);
    unsigned short* Wbf3 = (unsigned short*)al(sizeof(unsigned short) * 192 * HID);
    float* agg     = (float*)al(sizeof(float) * (size_t)N_NODES * 32);
    float* concat  = (float*)al(sizeof(float) * (size_t)N_NODES * 96);

    hipMemsetAsync(gcur, 0, sizeof(int) * NB, stream);

    k_prew<<<144, 256, 0, stream>>>(V1, comp1, loop1, V2, comp2, loop2,
                                    V3, comp3, loop3, Wbf1, Wbf2, Wbf3);
    k_bscatter<<<BS_BLOCKS, 256, 0, stream>>>(src, dst, etype, edge_mask, gcur, ebuf);
    k_bsort2<<<2 * NB, 512, 0, stream>>>(gcur, ebuf, esort, offsets);

    const int agrid = (N_NODES + 31) / 32;

    // layer 1
    k_transform_l1<<<1250, 256, 0, stream>>>(x, Wbf1, b1, (unsigned short*)xrel16, agg);
    k_agg<<<agrid, 256, 0, stream>>>(offsets, esort, xrel16, agg, concat, 0);

    // layer 2
    k_transform_reg32<<<784, 256, 0, stream>>>(concat + 0, 96, Wbf2, b2, (unsigned short*)xrel16, agg);
    k_agg<<<agrid, 256, 0, stream>>>(offsets, esort, xrel16, agg, concat, 32);

    // layer 3
    k_transform_reg32<<<784, 256, 0, stream>>>(concat + 32, 96, Wbf3, b3, (unsigned short*)xrel16, agg);
    k_agg<<<agrid, 256, 0, stream>>>(offsets, esort, xrel16, agg, concat, 64);

    k_mlp<<<N_PAIRS, 128, 0, stream>>>(concat, users_idx, items_idx, w1, bw1, w2, bw2, out);
}

// Round 12
// 355.132 us; speedup vs baseline: 1.0997x; 1.0662x over previous
//
#include <hip/hip_runtime.h>
#include <stdint.h>

#define N_NODES  100000
#define N_EDGES  1600000
#define IN_FEATS 128
#define HID      32
#define N_REL    5
#define N_BASES  2
#define N_PAIRS  4096

#define NB        196        // buckets of 512 dst nodes
#define BCAP      16384      // fixed slab per bucket (mean 8192, sigma ~90)
#define EPB       2048       // edges per scatter block
#define SC_BLOCKS 782        // ceil(1600000/2048)
#define NGROUPS   6250       // N_NODES/16

typedef __attribute__((ext_vector_type(8))) short short8;
typedef __attribute__((ext_vector_type(4))) float f32x4;

__device__ inline unsigned int pack_bf16(float a, float b) {
    unsigned int ua = __float_as_uint(a), ub = __float_as_uint(b);
    ua = (ua + 0x7fffu + ((ua >> 16) & 1u)) >> 16;
    ub = (ub + 0x7fffu + ((ub >> 16) & 1u)) >> 16;
    return ua | (ub << 16);
}

__device__ inline unsigned short bf16_1(float a) {
    unsigned int u = __float_as_uint(a);
    u = (u + 0x7fffu + ((u >> 16) & 1u)) >> 16;
    return (unsigned short)u;
}

// ---------------- FUSED: weight prep (blocks 0..143) + LDS-sorted bucket scatter ----------------
// scatter record: x = (dst&511)<<23 | (src*80 + etype*16), y = mask fp32
// bucket b's records at ebuf[b*BCAP .. b*BCAP+gcur[b]); block-local counting sort
// in LDS so the global flush is coalesced (consecutive threads -> consecutive addrs).

__global__ __launch_bounds__(256) void k_pre(
    const float* __restrict__ V1, const float* __restrict__ comp1, const float* __restrict__ loop1,
    const float* __restrict__ V2, const float* __restrict__ comp2, const float* __restrict__ loop2,
    const float* __restrict__ V3, const float* __restrict__ comp3, const float* __restrict__ loop3,
    unsigned short* __restrict__ Wbf1, unsigned short* __restrict__ Wbf2,
    unsigned short* __restrict__ Wbf3,
    const int* __restrict__ src, const int* __restrict__ dst,
    const int* __restrict__ etype, const float* __restrict__ mask,
    int* __restrict__ gcur, int2* __restrict__ ebuf) {
    int b = blockIdx.x;
    int t = threadIdx.x;
    if (b < 144) {
        const float *V, *comp, *loopw;
        unsigned short* Wbf;
        int D, idx;
        if (b < 96)      { V = V1; comp = comp1; loopw = loop1; Wbf = Wbf1; D = IN_FEATS; idx = b * 256 + t; }
        else if (b < 120){ V = V2; comp = comp2; loopw = loop2; Wbf = Wbf2; D = HID;      idx = (b - 96) * 256 + t; }
        else             { V = V3; comp = comp3; loopw = loop3; Wbf = Wbf3; D = HID;      idx = (b - 120) * 256 + t; }
        if (idx >= 192 * D) return;
        int j = idx / D, k = idx % D;
        float v;
        if (j < 160) {
            int r = j >> 5, o = j & 31;
            v = comp[r * 2 + 0] * V[(size_t)(0 * D + k) * 32 + o]
              + comp[r * 2 + 1] * V[(size_t)(1 * D + k) * 32 + o];
        } else {
            v = loopw[k * 32 + (j - 160)];
        }
        Wbf[idx] = bf16_1(v);
        return;
    }
    // ---------- scatter with block-local counting sort ----------
    __shared__ int lh[NB];        // histogram, then cursor
    __shared__ int lex[NB];       // local exclusive base
    __shared__ int gbase[NB];     // reserved global slab base
    __shared__ int scanbuf[256];
    __shared__ int2  srec[EPB];   // 16 KB sorted records
    __shared__ short sb[EPB];     // bucket id per sorted slot
    int blk = b - 144;
    int e0 = blk * EPB;
    if (t < NB) lh[t] = 0;
    __syncthreads();
    int2 rec[8];
    int  bk[8];
#pragma unroll
    for (int i = 0; i < 8; i++) {
        int e = e0 + t + i * 256;
        if (e < N_EDGES) {
            int d = dst[e];
            bk[i] = d >> 9;
            rec[i].x = ((d & 511) << 23) | (src[e] * 80 + etype[e] * 16);
            rec[i].y = __float_as_int(mask[e]);
            atomicAdd(&lh[bk[i]], 1);
        } else bk[i] = -1;
    }
    __syncthreads();
    int cnt = (t < NB) ? lh[t] : 0;
    scanbuf[t] = cnt;
    __syncthreads();
    for (int off = 1; off < 256; off <<= 1) {
        int v = (t >= off) ? scanbuf[t - off] : 0;
        __syncthreads();
        scanbuf[t] += v;
        __syncthreads();
    }
    if (t < NB) {
        lex[t] = scanbuf[t] - cnt;
        gbase[t] = t * BCAP + (cnt ? atomicAdd(&gcur[t], cnt) : 0);
        lh[t] = 0;   // reuse as sort cursor
    }
    __syncthreads();
#pragma unroll
    for (int i = 0; i < 8; i++) {
        if (bk[i] >= 0) {
            int p = lex[bk[i]] + atomicAdd(&lh[bk[i]], 1);
            srec[p] = rec[i];
            sb[p] = (short)bk[i];
        }
    }
    __syncthreads();
    int total = scanbuf[NB - 1];
    for (int idx = t; idx < total; idx += 256) {
        int bb = sb[idx];
        ebuf[gbase[bb] + (idx - lex[bb])] = srec[idx];
    }
}

// ---------------- per-half-bucket counting sort -> contiguous CSR (esort + offsets) ----------------

__global__ __launch_bounds__(512) void k_bsort2(
    const int* __restrict__ gcur, const int2* __restrict__ ebuf,
    int2* __restrict__ esort, int* __restrict__ offsets) {
    __shared__ int hist[512];
    __shared__ int incl[512];
    __shared__ int cur[512];
    __shared__ int bs[256];
    __shared__ int sBase, sCnt;
    int blk = blockIdx.x, b = blk >> 1, h = blk & 1, t = threadIdx.x;
    if (t < 256) bs[t] = (t < NB) ? gcur[t] : 0;
    __syncthreads();
    for (int off = 1; off < 256; off <<= 1) {
        int v = 0;
        if (t < 256 && t >= off) v = bs[t - off];
        __syncthreads();
        if (t < 256) bs[t] += v;
        __syncthreads();
    }
    if (t == 0) { sCnt = gcur[b]; sBase = bs[b] - gcur[b]; }
    hist[t] = 0;
    __syncthreads();
    int cnt = sCnt, gbase = sBase;
    const int2* slab = ebuf + (size_t)b * BCAP;
    for (int e = t; e < cnt; e += 512) {
        int dl = ((unsigned)slab[e].x) >> 23;
        atomicAdd(&hist[dl], 1);
    }
    __syncthreads();
    incl[t] = hist[t];
    __syncthreads();
    for (int off = 1; off < 512; off <<= 1) {
        int v = 0;
        if (t >= off) v = incl[t - off];
        __syncthreads();
        incl[t] += v;
        __syncthreads();
    }
    int ex = incl[t] - hist[t];
    cur[t] = ex;
    if ((t >> 8) == h) {
        int n = (b << 9) + t;
        if (n <= N_NODES) offsets[n] = gbase + ex;
    }
    if (b == NB - 1 && h == 1 && t == 0) offsets[N_NODES] = N_EDGES;
    __syncthreads();
    for (int e = t; e < cnt; e += 512) {
        int2 pk = slab[e];
        int dl = ((unsigned)pk.x) >> 23;
        if ((dl >> 8) == h) {
            int pos = gbase + atomicAdd(&cur[dl], 1);
            int2 rec;
            rec.x = pk.x & 0x7fffff;
            rec.y = pk.y;
            esort[pos] = rec;
        }
    }
}

// ---------------- transform L1 (D=128): wave-specialized MFMA ----------------

__global__ __launch_bounds__(256) void k_transform_l1(
    const float* __restrict__ xin,
    const unsigned short* __restrict__ Wbf, const float* __restrict__ bias,
    unsigned short* __restrict__ xs16, float* __restrict__ aggout) {
    __shared__ unsigned short As[16 * 136];
    int t = threadIdx.x;
    int wv = t >> 6, lane = t & 63;
    int q = lane >> 4, n16 = lane & 15;
    short8 bfr[3][4];
#pragma unroll
    for (int i = 0; i < 3; i++) {
        int tt = wv * 3 + i;
#pragma unroll
        for (int ks = 0; ks < 4; ks++)
            bfr[i][ks] = *(const short8*)(Wbf + (tt * 16 + n16) * 128 + ks * 32 + q * 8);
    }
    float bv0 = bias[n16], bv1 = bias[16 + n16];
    int node_l = t >> 4;
    int seg    = t & 15;
    int g0 = blockIdx.x * 5;
    float4 p0, p1;
    {
        const float* xr = xin + ((size_t)(g0 * 16 + node_l)) * 128 + seg * 8;
        p0 = *(const float4*)xr;
        p1 = *(const float4*)(xr + 4);
    }
    for (int gi = 0; gi < 5; gi++) {
        int g = g0 + gi;
        int n0 = g * 16;
        __syncthreads();
        {
            unsigned int u0 = pack_bf16(p0.x, p0.y);
            unsigned int u1 = pack_bf16(p0.z, p0.w);
            unsigned int u2 = pack_bf16(p1.x, p1.y);
            unsigned int u3 = pack_bf16(p1.z, p1.w);
            uint4 v; v.x = u0; v.y = u1; v.z = u2; v.w = u3;
            *(uint4*)(As + node_l * 136 + seg * 8) = v;
        }
        __syncthreads();
        if (gi + 1 < 5) {
            const float* xr = xin + ((size_t)((g + 1) * 16 + node_l)) * 128 + seg * 8;
            p0 = *(const float4*)xr;
            p1 = *(const float4*)(xr + 4);
        }
        short8 afr[4];
#pragma unroll
        for (int ks = 0; ks < 4; ks++)
            afr[ks] = *(const short8*)(As + n16 * 136 + ks * 32 + q * 8);
        f32x4 d[3];
        f32x4 z = {0.f, 0.f, 0.f, 0.f};
#pragma unroll
        for (int i = 0; i < 3; i++) d[i] = z;
#pragma unroll
        for (int i = 0; i < 3; i++)
#pragma unroll
            for (int ks = 0; ks < 4; ks++)
                d[i] = __builtin_amdgcn_mfma_f32_16x16x32_bf16(afr[ks], bfr[i][ks], d[i], 0, 0, 0);
#pragma unroll
        for (int i = 0; i < 3; i++) {
            int tt = wv * 3 + i;
            if (tt < 10) {
#pragma unroll
                for (int r = 0; r < 4; r++) {
                    int node = n0 + q * 4 + r;
                    xs16[(size_t)node * 160 + tt * 16 + n16] = bf16_1(d[i][r]);
                }
            } else {
                float bv = (tt == 10) ? bv0 : bv1;
                int o = (tt - 10) * 16 + n16;
#pragma unroll
                for (int r = 0; r < 4; r++) {
                    int node = n0 + q * 4 + r;
                    aggout[(size_t)node * 32 + o] = d[i][r] + bv;
                }
            }
        }
    }
}

// ---------------- transform L2/L3 (D=32): B in registers, no LDS, no barrier ----------------

__global__ __launch_bounds__(256) void k_transform_reg32(
    const float* __restrict__ xin, int xstride,
    const unsigned short* __restrict__ Wbf, const float* __restrict__ bias,
    unsigned short* __restrict__ xs16, float* __restrict__ aggout) {
    int t = threadIdx.x;
    int wv = t >> 6, lane = t & 63;
    int q = lane >> 4, n16 = lane & 15;
    short8 bfr[12];
#pragma unroll
    for (int t12 = 0; t12 < 12; t12++)
        bfr[t12] = *(const short8*)(Wbf + (t12 * 16 + n16) * 32 + q * 8);
    float bv0 = bias[n16], bv1 = bias[16 + n16];
    int gstep = gridDim.x * 4;
    int g = blockIdx.x * 4 + wv;
    float4 x0, x1;
    if (g < NGROUPS) {
        const float* xr = xin + (size_t)(g * 16 + n16) * xstride + q * 8;
        x0 = *(const float4*)(xr);
        x1 = *(const float4*)(xr + 4);
    }
    while (g < NGROUPS) {
        int gn = g + gstep;
        union { unsigned int u[4]; short8 s; } cv;
        cv.u[0] = pack_bf16(x0.x, x0.y);
        cv.u[1] = pack_bf16(x0.z, x0.w);
        cv.u[2] = pack_bf16(x1.x, x1.y);
        cv.u[3] = pack_bf16(x1.z, x1.w);
        short8 afr = cv.s;
        float4 nx0, nx1;
        if (gn < NGROUPS) {
            const float* xr = xin + (size_t)(gn * 16 + n16) * xstride + q * 8;
            nx0 = *(const float4*)(xr);
            nx1 = *(const float4*)(xr + 4);
        }
        f32x4 d[12];
        f32x4 z = {0.f, 0.f, 0.f, 0.f};
#pragma unroll
        for (int i = 0; i < 12; i++) d[i] = z;
#pragma unroll
        for (int t12 = 0; t12 < 12; t12++)
            d[t12] = __builtin_amdgcn_mfma_f32_16x16x32_bf16(afr, bfr[t12], d[t12], 0, 0, 0);
        int n0 = g * 16;
#pragma unroll
        for (int t12 = 0; t12 < 10; t12++) {
#pragma unroll
            for (int r = 0; r < 4; r++) {
                int node = n0 + q * 4 + r;
                xs16[(size_t)node * 160 + t12 * 16 + n16] = bf16_1(d[t12][r]);
            }
        }
#pragma unroll
        for (int r = 0; r < 4; r++) {
            int node = n0 + q * 4 + r;
            aggout[(size_t)node * 32 + n16]      = d[10][r] + bv0;
            aggout[(size_t)node * 32 + 16 + n16] = d[11][r] + bv1;
        }
        x0 = nx0; x1 = nx1; g = gn;
    }
}

// ---------------- aggregation: 8 lanes/node, uint2 gathers, 16-deep, reg accumulate ----------------

__global__ __launch_bounds__(256) void k_agg(
    const int* __restrict__ offsets, const int2* __restrict__ esort,
    const unsigned int* __restrict__ xrel16, const float* __restrict__ agg,
    float* __restrict__ hout, int hoff) {
    int v = blockIdx.x * 32 + (threadIdx.x >> 3);
    int o = threadIdx.x & 7;
    if (v >= N_NODES) return;
    int s0 = offsets[v], s1 = offsets[v + 1];
    float4 a0 = *(const float4*)(agg + (size_t)v * 32 + o * 4);
    float acc0 = a0.x, acc1 = a0.y, acc2 = a0.z, acc3 = a0.w;
    int last = s1 - 1;
    for (int e = s0; e < s1; e += 16) {
        int addr[16];
        float m[16];
#pragma unroll
        for (int i = 0; i < 16; i++) {
            int ei = e + i;
            int ec = (ei <= last) ? ei : last;
            int2 pk = esort[ec];
            addr[i] = pk.x;
            m[i] = (ei <= last) ? __int_as_float(pk.y) : 0.f;
        }
        uint2 xw[16];
#pragma unroll
        for (int i = 0; i < 16; i++)
            xw[i] = *(const uint2*)(xrel16 + (unsigned)addr[i] + o * 2);
#pragma unroll
        for (int i = 0; i < 16; i++) {
            float f0 = __uint_as_float(xw[i].x << 16);
            float f1 = __uint_as_float(xw[i].x & 0xffff0000u);
            float f2 = __uint_as_float(xw[i].y << 16);
            float f3 = __uint_as_float(xw[i].y & 0xffff0000u);
            acc0 = fmaf(m[i], f0, acc0);
            acc1 = fmaf(m[i], f1, acc1);
            acc2 = fmaf(m[i], f2, acc2);
            acc3 = fmaf(m[i], f3, acc3);
        }
    }
    float4 r;
    r.x = tanhf(acc0); r.y = tanhf(acc1); r.z = tanhf(acc2); r.w = tanhf(acc3);
    *(float4*)(hout + (size_t)v * 96 + hoff + o * 4) = r;
}

// ---------------- MLP head ----------------

__global__ void k_mlp(const float* __restrict__ concat, const int* __restrict__ uidx,
                      const int* __restrict__ iidx,
                      const float* __restrict__ w1, const float* __restrict__ bw1,
                      const float* __restrict__ w2, const float* __restrict__ bw2,
                      float* __restrict__ out) {
    __shared__ float feats[192];
    __shared__ float red[2];
    int p = blockIdx.x;
    int t = threadIdx.x;   // 128 threads
    int u = uidx[p], it = iidx[p];
    for (int k = t; k < 192; k += 128)
        feats[k] = (k < 96) ? concat[(size_t)u * 96 + k] : concat[(size_t)it * 96 + (k - 96)];
    __syncthreads();
    float acc = bw1[t];
    for (int k = 0; k < 192; k++) acc += feats[k] * w1[k * 128 + t];
    float h = fmaxf(acc, 0.f);
    float part = h * w2[t];
    for (int off = 32; off > 0; off >>= 1) part += __shfl_down(part, off, 64);
    if ((t & 63) == 0) red[t >> 6] = part;
    __syncthreads();
    if (t == 0) out[p] = red[0] + red[1] + bw2[0];
}

// ---------------- launch ----------------

extern "C" void kernel_launch(void* const* d_in, const int* in_sizes, int n_in,
                              void* d_out, int out_size, void* d_ws, size_t ws_size,
                              hipStream_t stream) {
    const float* x         = (const float*)d_in[0];
    const float* edge_mask = (const float*)d_in[1];
    const int*   etype     = (const int*)d_in[2];
    const int*   src       = (const int*)d_in[3];
    const int*   dst       = (const int*)d_in[4];
    const int*   users_idx = (const int*)d_in[5];
    const int*   items_idx = (const int*)d_in[6];
    const float* V1        = (const float*)d_in[7];
    const float* comp1     = (const float*)d_in[8];
    const float* loop1     = (const float*)d_in[9];
    const float* b1        = (const float*)d_in[10];
    const float* V2        = (const float*)d_in[11];
    const float* comp2     = (const float*)d_in[12];
    const float* loop2     = (const float*)d_in[13];
    const float* b2        = (const float*)d_in[14];
    const float* V3        = (const float*)d_in[15];
    const float* comp3     = (const float*)d_in[16];
    const float* loop3     = (const float*)d_in[17];
    const float* b3        = (const float*)d_in[18];
    const float* w1        = (const float*)d_in[19];
    const float* bw1       = (const float*)d_in[20];
    const float* w2        = (const float*)d_in[21];
    const float* bw2       = (const float*)d_in[22];
    float* out = (float*)d_out;

    uintptr_t w = (uintptr_t)d_ws;
    auto al = [&](size_t bytes) { uintptr_t p = (w + 255) & ~(uintptr_t)255; w = p + bytes; return p; };
    int*   gcur    = (int*)al(sizeof(int) * NB);
    int*   offsets = (int*)al(sizeof(int) * (N_NODES + 1));
    int2*  ebuf    = (int2*)al(sizeof(int2) * (size_t)NB * BCAP);   // fixed slabs
    unsigned int* xrel16 = (unsigned int*)al(sizeof(unsigned int) * (size_t)N_NODES * 80);
    int2*  esort   = (int2*)al(sizeof(int2) * N_EDGES);
    unsigned short* Wbf1 = (unsigned short*)al(sizeof(unsigned short) * 192 * IN_FEATS);
    unsigned short* Wbf2 = (unsigned short*)al(sizeof(unsigned short) * 192 * HID);
    unsigned short* Wbf3 = (unsigned short*)al(sizeof(unsigned short) * 192 * HID);
    float* agg     = (float*)al(sizeof(float) * (size_t)N_NODES * 32);
    float* concat  = (float*)al(sizeof(float) * (size_t)N_NODES * 96);

    hipMemsetAsync(gcur, 0, sizeof(int) * NB, stream);

    k_pre<<<144 + SC_BLOCKS, 256, 0, stream>>>(V1, comp1, loop1, V2, comp2, loop2,
                                               V3, comp3, loop3, Wbf1, Wbf2, Wbf3,
                                               src, dst, etype, edge_mask, gcur, ebuf);
    k_bsort2<<<2 * NB, 512, 0, stream>>>(gcur, ebuf, esort, offsets);

    const int agrid = (N_NODES + 31) / 32;

    // layer 1
    k_transform_l1<<<1250, 256, 0, stream>>>(x, Wbf1, b1, (unsigned short*)xrel16, agg);
    k_agg<<<agrid, 256, 0, stream>>>(offsets, esort, xrel16, agg, concat, 0);

    // layer 2
    k_transform_reg32<<<784, 256, 0, stream>>>(concat + 0, 96, Wbf2, b2, (unsigned short*)xrel16, agg);
    k_agg<<<agrid, 256, 0, stream>>>(offsets, esort, xrel16, agg, concat, 32);

    // layer 3
    k_transform_reg32<<<784, 256, 0, stream>>>(concat + 32, 96, Wbf3, b3, (unsigned short*)xrel16, agg);
    k_agg<<<agrid, 256, 0, stream>>>(offsets, esort, xrel16, agg, concat, 64);

    k_mlp<<<N_PAIRS, 128, 0, stream>>>(concat, users_idx, items_idx, w1, bw1, w2, bw2, out);
}